// Round 17
// baseline (38.353 us; speedup 1.0000x reference)
//
#include <hip/hip_runtime.h>

#define F_IN    32768
#define HID     64
#define NB_OBJ  16
#define BATCH   64
#define N_AGENTS 4
#define N_ACT   13
#define NEG_SLOPE 0.01f

#define FC      64               // f-chunk width per fused block
#define NCHUNK  (F_IN / FC)      // 512 split-K chunks

typedef float f32x4 __attribute__((ext_vector_type(4)));

// static scratch: g_part[BATCH][NCHUNK][HID] = 8 MiB ([b][chunk][h])
__device__ float g_part[BATCH * NCHUNK * HID];

// ---------------------------------------------------------------------------
// K1: fused node-mean + partial GEMM, lane=batch step B.
// grid = NCHUNK (512), block = 512 (8 waves).
// xbar: unpadded [64][64] with XOR quad-swizzle (quad ^= b&7): step-A b128
// writes, step-B lane=b b128 reads, and the epilogue transpose all run at
// the 8-cyc LDS floor. Step B: 16 ds_read_b128 per wave (was 128 broadcast
// reads); w enters via wave-uniform s_load (h0 readfirstlane'd).
// ---------------------------------------------------------------------------
__global__ __launch_bounds__(512, 4)
void k_fused(const float* __restrict__ u, const float* __restrict__ w) {
    __shared__ float xbar[BATCH * FC];      // 16 KiB, swizzled
    const int t    = threadIdx.x;
    const int blk  = blockIdx.x;
    const int f0   = blk * FC;
    const int lane = t & 63;
    const int wv   = t >> 6;                // 0..7

    // ---- step A: xbar[b][f] = (1/16) * sum_o u[b][o][f0+f] (swizzled) ----
    {
        const int b  = t >> 3;
        const int j  = t & 7;
        const int bq = b & 7;
        const float* up = u + (size_t)b * (NB_OBJ * F_IN) + f0 + j * 4;
        f32x4 a0 = (f32x4)(0.f);
        f32x4 a1 = (f32x4)(0.f);
        #pragma unroll
        for (int o = 0; o < NB_OBJ; ++o) {
            const float* ro = up + (size_t)o * F_IN;
            a0 += *reinterpret_cast<const f32x4*>(ro);
            a1 += *reinterpret_cast<const f32x4*>(ro + 32);
        }
        const float inv = 1.0f / (float)NB_OBJ;
        a0 *= inv;
        a1 *= inv;
        // content quad j -> location quad j^bq; quad j+8 -> (j^bq)+8
        *reinterpret_cast<f32x4*>(&xbar[b * 64 + ((j ^ bq) << 2)])      = a0;
        *reinterpret_cast<f32x4*>(&xbar[b * 64 + ((j ^ bq) << 2) + 32]) = a1;
    }
    __syncthreads();

    // ---- step B: lane = batch, wave wv -> h-slice h0..h0+7 ----
    const int h0 = __builtin_amdgcn_readfirstlane(wv) * 8;  // uniform
    const int bq = lane & 7;
    f32x4 accA = (f32x4)(0.f), accB = (f32x4)(0.f);
    #pragma unroll
    for (int g = 0; g < 8; ++g) {           // f = 8g .. 8g+7
        f32x4 x0 = *reinterpret_cast<const f32x4*>(
            &xbar[lane * 64 + (((2 * g) ^ bq) << 2)]);
        f32x4 x1 = *reinterpret_cast<const f32x4*>(
            &xbar[lane * 64 + (((2 * g + 1) ^ bq) << 2)]);
        #pragma unroll
        for (int e = 0; e < 4; ++e) {       // f = 8g+e
            const float* wp = w + (size_t)(f0 + 8 * g + e) * HID + h0;  // uniform
            #pragma unroll
            for (int k = 0; k < 4; ++k) accA[k] += x0[e] * wp[k];
            #pragma unroll
            for (int k = 0; k < 4; ++k) accB[k] += x0[e] * wp[4 + k];
        }
        #pragma unroll
        for (int e = 0; e < 4; ++e) {       // f = 8g+4+e
            const float* wp = w + (size_t)(f0 + 8 * g + 4 + e) * HID + h0;
            #pragma unroll
            for (int k = 0; k < 4; ++k) accA[k] += x1[e] * wp[k];
            #pragma unroll
            for (int k = 0; k < 4; ++k) accB[k] += x1[e] * wp[4 + k];
        }
    }
    __syncthreads();   // all xbar reads done before overwrite

    // ---- epilogue: transpose acc through LDS, then coalesced store ----
    {
        const int q0 = h0 >> 2;             // 2*wv
        *reinterpret_cast<f32x4*>(&xbar[lane * 64 + ((q0 ^ bq) << 2)])       = accA;
        *reinterpret_cast<f32x4*>(&xbar[lane * 64 + (((q0 + 1) ^ bq) << 2)]) = accB;
    }
    __syncthreads();
    {
        #pragma unroll
        for (int bb = 0; bb < 8; ++bb) {
            const int b = wv * 8 + bb;      // b&7 == bb (compile-time)
            float v = xbar[b * 64 + ((((lane >> 2) ^ bb)) << 2) + (lane & 3)];
            g_part[((size_t)b * NCHUNK + blk) * HID + lane] = v;
        }
    }
}

// ---------------------------------------------------------------------------
// K2: merged tail (R14 proven, verbatim). grid = BATCH (64), block = 1024.
// ---------------------------------------------------------------------------
__global__ __launch_bounds__(1024)
void k_tail(const float* __restrict__ gcn_b,
            const float* __restrict__ w1, const float* __restrict__ b1,
            const float* __restrict__ w2, const float* __restrict__ b2,
            const float* __restrict__ actions, float* __restrict__ out) {
    const int b = blockIdx.x;
    const int t = threadIdx.x;
    __shared__ float red[16][HID];
    __shared__ float pooled[HID];
    __shared__ float zbuf[N_AGENTS][HID];
    __shared__ float qbuf[N_AGENTS][N_ACT];

    // phase 1: red[kg][h] = sum of this kg's 32 chunks (contiguous 8KB each)
    {
        const int h  = t & 63;
        const int kg = t >> 6;   // 0..15
        const float* p = g_part + ((size_t)b * NCHUNK + kg * 32) * HID + h;
        float acc = 0.f;
        #pragma unroll
        for (int i = 0; i < 32; ++i)
            acc += p[(size_t)i * HID];
        red[kg][h] = acc;
    }
    __syncthreads();
    if (t < HID) {
        float acc = gcn_b[t];
        #pragma unroll
        for (int kg = 0; kg < 16; ++kg) acc += red[kg][t];
        pooled[t] = acc;
    }
    __syncthreads();

    // phase 2: z[a][k] = leaky(b1 + sum_h pooled[h] * w1[a][h][k])
    if (t < N_AGENTS * HID) {
        const int a = t >> 6, k = t & 63;
        const float* w1p = w1 + a * (HID * HID) + k;
        float acc = b1[a * HID + k];
        #pragma unroll
        for (int hh = 0; hh < HID; ++hh) acc += pooled[hh] * w1p[hh * HID];
        zbuf[a][k] = (acc >= 0.f) ? acc : NEG_SLOPE * acc;
    }
    __syncthreads();

    // phase 3: q[a][c] = b2 + sum_h z[a][h] * w2[a][h][c]
    if (t < N_AGENTS * N_ACT) {
        const int a = t / N_ACT, c = t % N_ACT;
        const float* w2p = w2 + a * (HID * N_ACT) + c;
        float acc = b2[a * N_ACT + c];
        #pragma unroll
        for (int hh = 0; hh < HID; ++hh) acc += zbuf[a][hh] * w2p[hh * N_ACT];
        qbuf[a][c] = acc;
    }
    __syncthreads();

    // phase 4: argmax over actions (first-max, matching jnp.argmax), gather
    if (t < N_AGENTS) {
        const float* ap = actions + ((size_t)t * BATCH + b) * N_ACT;
        int best = 0; float bv = ap[0];
        for (int c = 1; c < N_ACT; ++c) {
            float v = ap[c];
            if (v > bv) { bv = v; best = c; }
        }
        out[t * BATCH + b] = qbuf[t][best];
    }
}

extern "C" void kernel_launch(void* const* d_in, const int* in_sizes, int n_in,
                              void* d_out, int out_size, void* d_ws, size_t ws_size,
                              hipStream_t stream) {
    const float* u   = (const float*)d_in[0];
    // d_in[1] = binary_tensor: dead in the reference computation
    const float* act = (const float*)d_in[2];
    const float* gw  = (const float*)d_in[3];
    const float* gb  = (const float*)d_in[4];
    const float* w1  = (const float*)d_in[5];
    const float* b1  = (const float*)d_in[6];
    const float* w2  = (const float*)d_in[7];
    const float* b2  = (const float*)d_in[8];
    float* out = (float*)d_out;

    hipLaunchKernelGGL(k_fused, dim3(NCHUNK), dim3(512),  0, stream, u, gw);
    hipLaunchKernelGGL(k_tail,  dim3(BATCH),  dim3(1024), 0, stream,
                       gb, w1, b1, w2, b2, act, out);
}

// Round 18
// 36.265 us; speedup vs baseline: 1.0576x; 1.0576x over previous
//
#include <hip/hip_runtime.h>

#define F_IN    32768
#define HID     64
#define NB_OBJ  16
#define BATCH   64
#define N_AGENTS 4
#define N_ACT   13
#define NEG_SLOPE 0.01f

#define FC      64               // f-chunk width per fused block
#define NCHUNK  (F_IN / FC)      // 512 split-K chunks

typedef float f32x4 __attribute__((ext_vector_type(4)));

// static scratch: g_part[BATCH][NCHUNK][HID] = 8 MiB ([b][chunk][h])
__device__ float g_part[BATCH * NCHUNK * HID];

// ---------------------------------------------------------------------------
// K1: fused node-mean + partial GEMM (R14 proven body, verbatim).
// grid = NCHUNK (512), block = 512 (8 waves).
// ---------------------------------------------------------------------------
__global__ __launch_bounds__(512, 4)
void k_fused(const float* __restrict__ u, const float* __restrict__ w) {
    __shared__ float xbar[BATCH][FC + 4];   // row pitch 68 floats
    const int t    = threadIdx.x;
    const int blk  = blockIdx.x;
    const int f0   = blk * FC;
    const int lane = t & 63;
    const int wv   = t >> 6;                // 0..7

    float wreg[FC];
    {
        const float* wp = w + (size_t)f0 * HID + lane;
        #pragma unroll
        for (int f = 0; f < FC; ++f) wreg[f] = wp[f * HID];
    }

    // step A: xbar[b][f] = (1/16) * sum_o u[b][o][f0+f]
    {
        const int b = t >> 3;
        const int j = t & 7;
        const float* up = u + (size_t)b * (NB_OBJ * F_IN) + f0 + j * 4;
        f32x4 a0 = (f32x4)(0.f);
        f32x4 a1 = (f32x4)(0.f);
        #pragma unroll
        for (int o = 0; o < NB_OBJ; ++o) {
            const float* ro = up + (size_t)o * F_IN;
            a0 += *reinterpret_cast<const f32x4*>(ro);
            a1 += *reinterpret_cast<const f32x4*>(ro + 32);
        }
        const float inv = 1.0f / (float)NB_OBJ;
        a0 *= inv;
        a1 *= inv;
        *reinterpret_cast<f32x4*>(&xbar[b][j * 4])      = a0;
        *reinterpret_cast<f32x4*>(&xbar[b][32 + j * 4]) = a1;
    }
    __syncthreads();

    // step B: wave -> 8 batches; lane = h; store [b][blk][h] (256B rows).
    {
        #pragma unroll
        for (int bb = 0; bb < 8; ++bb) {
            const int b = wv * 8 + bb;
            float acc = 0.f;
            #pragma unroll
            for (int fq = 0; fq < FC / 4; ++fq) {
                f32x4 xb = *reinterpret_cast<const f32x4*>(&xbar[b][fq * 4]);
                acc += xb.x * wreg[fq * 4 + 0];
                acc += xb.y * wreg[fq * 4 + 1];
                acc += xb.z * wreg[fq * 4 + 2];
                acc += xb.w * wreg[fq * 4 + 3];
            }
            g_part[((size_t)b * NCHUNK + blk) * HID + lane] = acc;
        }
    }
}

// ---------------------------------------------------------------------------
// K2: merged tail, float4 phase-1 reads. grid = BATCH (64), block = 1024.
// phase 1: thread (g = t>>4 in 0..63, l = t&15) sums 8 contiguous chunks as
// float4 (per wave-instr: 4 rows x 256 B = 1 KiB contiguous; 4x bytes per
// outstanding-load slot vs the scalar version). 2-level LDS combine.
// ---------------------------------------------------------------------------
__global__ __launch_bounds__(1024)
void k_tail(const float* __restrict__ gcn_b,
            const float* __restrict__ w1, const float* __restrict__ b1,
            const float* __restrict__ w2, const float* __restrict__ b2,
            const float* __restrict__ actions, float* __restrict__ out) {
    const int b = blockIdx.x;
    const int t = threadIdx.x;
    __shared__ float red[64][HID];   // [g][h]
    __shared__ float red2[4][HID];
    __shared__ float pooled[HID];
    __shared__ float zbuf[N_AGENTS][HID];
    __shared__ float qbuf[N_AGENTS][N_ACT];

    // phase 1a: group g sums its 8 contiguous chunks, float4-wide.
    {
        const int l = t & 15;        // float4 column (h = 4l..4l+3)
        const int g = t >> 4;        // 0..63
        const f32x4* p = reinterpret_cast<const f32x4*>(
            g_part + ((size_t)b * NCHUNK + g * 8) * HID) + l;
        f32x4 a = (f32x4)(0.f);
        #pragma unroll
        for (int i = 0; i < 8; ++i)
            a += p[(size_t)i * 16];
        *reinterpret_cast<f32x4*>(&red[g][l * 4]) = a;
    }
    __syncthreads();
    // phase 1b: 4 groups x 16 g-rows each
    if (t < 4 * HID) {
        const int h  = t & 63;
        const int kg = t >> 6;       // 0..3
        float acc = 0.f;
        #pragma unroll
        for (int gg = 0; gg < 16; ++gg)
            acc += red[kg * 16 + gg][h];
        red2[kg][h] = acc;
    }
    __syncthreads();
    if (t < HID)
        pooled[t] = gcn_b[t] + red2[0][t] + red2[1][t] + red2[2][t] + red2[3][t];
    __syncthreads();

    // phase 2: z[a][k] = leaky(b1 + sum_h pooled[h] * w1[a][h][k])
    if (t < N_AGENTS * HID) {
        const int a = t >> 6, k = t & 63;
        const float* w1p = w1 + a * (HID * HID) + k;
        float acc = b1[a * HID + k];
        #pragma unroll
        for (int hh = 0; hh < HID; ++hh) acc += pooled[hh] * w1p[hh * HID];
        zbuf[a][k] = (acc >= 0.f) ? acc : NEG_SLOPE * acc;
    }
    __syncthreads();

    // phase 3: q[a][c] = b2 + sum_h z[a][h] * w2[a][h][c]
    if (t < N_AGENTS * N_ACT) {
        const int a = t / N_ACT, c = t % N_ACT;
        const float* w2p = w2 + a * (HID * N_ACT) + c;
        float acc = b2[a * N_ACT + c];
        #pragma unroll
        for (int hh = 0; hh < HID; ++hh) acc += zbuf[a][hh] * w2p[hh * N_ACT];
        qbuf[a][c] = acc;
    }
    __syncthreads();

    // phase 4: argmax over actions (first-max, matching jnp.argmax), gather
    if (t < N_AGENTS) {
        const float* ap = actions + ((size_t)t * BATCH + b) * N_ACT;
        int best = 0; float bv = ap[0];
        for (int c = 1; c < N_ACT; ++c) {
            float v = ap[c];
            if (v > bv) { bv = v; best = c; }
        }
        out[t * BATCH + b] = qbuf[t][best];
    }
}

extern "C" void kernel_launch(void* const* d_in, const int* in_sizes, int n_in,
                              void* d_out, int out_size, void* d_ws, size_t ws_size,
                              hipStream_t stream) {
    const float* u   = (const float*)d_in[0];
    // d_in[1] = binary_tensor: dead in the reference computation
    const float* act = (const float*)d_in[2];
    const float* gw  = (const float*)d_in[3];
    const float* gb  = (const float*)d_in[4];
    const float* w1  = (const float*)d_in[5];
    const float* b1  = (const float*)d_in[6];
    const float* w2  = (const float*)d_in[7];
    const float* b2  = (const float*)d_in[8];
    float* out = (float*)d_out;

    hipLaunchKernelGGL(k_fused, dim3(NCHUNK), dim3(512),  0, stream, u, gw);
    hipLaunchKernelGGL(k_tail,  dim3(BATCH),  dim3(1024), 0, stream,
                       gb, w1, b1, w2, b2, act, out);
}

// Round 19
// 36.177 us; speedup vs baseline: 1.0602x; 1.0024x over previous
//
#include <hip/hip_runtime.h>

#define F_IN    32768
#define HID     64
#define NB_OBJ  16
#define BATCH   64
#define N_AGENTS 4
#define N_ACT   13
#define NEG_SLOPE 0.01f

#define FC      64               // f-chunk width per fused block
#define NCHUNK  (F_IN / FC)      // 512 split-K chunks

typedef float f32x4 __attribute__((ext_vector_type(4)));

// static scratch: g_part[BATCH][NCHUNK][HID] = 8 MiB ([b][chunk][h])
__device__ float g_part[BATCH * NCHUNK * HID];

// ---------------------------------------------------------------------------
// K1: fused node-mean + partial GEMM — BARRIER-FREE.
// grid = NCHUNK (512), block = 512 (8 waves).
// Key fact: xbar is wave-private. Step A: wave wv (t = 64wv..64wv+63) writes
// rows b = t>>3 = 8wv..8wv+7. Step B: wave wv reads rows 8wv+bb, bb=0..7.
// No cross-wave sharing -> the former __syncthreads only caused the barrier
// drain (vmcnt(0) convoy to the slowest load). Without it, each wave flows
// from its own loads into its own FMAs; waves self-pipeline and step-B
// compute hides under other waves' HBM streams. Same FP order -> absmax 0.
// ---------------------------------------------------------------------------
__global__ __launch_bounds__(512, 4)
void k_fused(const float* __restrict__ u, const float* __restrict__ w) {
    __shared__ float xbar[BATCH][FC + 4];   // row pitch 68 floats
    const int t    = threadIdx.x;
    const int blk  = blockIdx.x;
    const int f0   = blk * FC;
    const int lane = t & 63;
    const int wv   = t >> 6;                // 0..7

    float wreg[FC];
    {
        const float* wp = w + (size_t)f0 * HID + lane;
        #pragma unroll
        for (int f = 0; f < FC; ++f) wreg[f] = wp[f * HID];
    }

    // step A: xbar[b][f] = (1/16) * sum_o u[b][o][f0+f]   (wave-private rows)
    {
        const int b = t >> 3;
        const int j = t & 7;
        const float* up = u + (size_t)b * (NB_OBJ * F_IN) + f0 + j * 4;
        f32x4 a0 = (f32x4)(0.f);
        f32x4 a1 = (f32x4)(0.f);
        #pragma unroll
        for (int o = 0; o < NB_OBJ; ++o) {
            const float* ro = up + (size_t)o * F_IN;
            a0 += *reinterpret_cast<const f32x4*>(ro);
            a1 += *reinterpret_cast<const f32x4*>(ro + 32);
        }
        const float inv = 1.0f / (float)NB_OBJ;
        a0 *= inv;
        a1 *= inv;
        *reinterpret_cast<f32x4*>(&xbar[b][j * 4])      = a0;
        *reinterpret_cast<f32x4*>(&xbar[b][32 + j * 4]) = a1;
    }
    // NO __syncthreads(): same-wave DS ordering + compiler lgkmcnt waits
    // cover the ds_write -> ds_read dependency within each wave.

    // step B: wave -> its own 8 batches; lane = h; store [b][blk][h].
    {
        #pragma unroll
        for (int bb = 0; bb < 8; ++bb) {
            const int b = wv * 8 + bb;
            float acc = 0.f;
            #pragma unroll
            for (int fq = 0; fq < FC / 4; ++fq) {
                f32x4 xb = *reinterpret_cast<const f32x4*>(&xbar[b][fq * 4]);
                acc += xb.x * wreg[fq * 4 + 0];
                acc += xb.y * wreg[fq * 4 + 1];
                acc += xb.z * wreg[fq * 4 + 2];
                acc += xb.w * wreg[fq * 4 + 3];
            }
            g_part[((size_t)b * NCHUNK + blk) * HID + lane] = acc;
        }
    }
}

// ---------------------------------------------------------------------------
// K2: merged tail (R18). grid = BATCH (64), block = 1024 (16 waves).
// ---------------------------------------------------------------------------
__global__ __launch_bounds__(1024)
void k_tail(const float* __restrict__ gcn_b,
            const float* __restrict__ w1, const float* __restrict__ b1,
            const float* __restrict__ w2, const float* __restrict__ b2,
            const float* __restrict__ actions, float* __restrict__ out) {
    const int b = blockIdx.x;
    const int t = threadIdx.x;
    __shared__ float red[64][HID];   // [g][h]
    __shared__ float red2[4][HID];
    __shared__ float pooled[HID];
    __shared__ float zbuf[N_AGENTS][HID];
    __shared__ float qbuf[N_AGENTS][N_ACT];

    // phase 1a: group g sums its 8 contiguous chunks, float4-wide.
    {
        const int l = t & 15;        // float4 column (h = 4l..4l+3)
        const int g = t >> 4;        // 0..63
        const f32x4* p = reinterpret_cast<const f32x4*>(
            g_part + ((size_t)b * NCHUNK + g * 8) * HID) + l;
        f32x4 a = (f32x4)(0.f);
        #pragma unroll
        for (int i = 0; i < 8; ++i)
            a += p[(size_t)i * 16];
        *reinterpret_cast<f32x4*>(&red[g][l * 4]) = a;
    }
    __syncthreads();
    // phase 1b: 4 groups x 16 g-rows each
    if (t < 4 * HID) {
        const int h  = t & 63;
        const int kg = t >> 6;       // 0..3
        float acc = 0.f;
        #pragma unroll
        for (int gg = 0; gg < 16; ++gg)
            acc += red[kg * 16 + gg][h];
        red2[kg][h] = acc;
    }
    __syncthreads();
    if (t < HID)
        pooled[t] = gcn_b[t] + red2[0][t] + red2[1][t] + red2[2][t] + red2[3][t];
    __syncthreads();

    // phase 2: z[a][k] = leaky(b1 + sum_h pooled[h] * w1[a][h][k])
    if (t < N_AGENTS * HID) {
        const int a = t >> 6, k = t & 63;
        const float* w1p = w1 + a * (HID * HID) + k;
        float acc = b1[a * HID + k];
        #pragma unroll
        for (int hh = 0; hh < HID; ++hh) acc += pooled[hh] * w1p[hh * HID];
        zbuf[a][k] = (acc >= 0.f) ? acc : NEG_SLOPE * acc;
    }
    __syncthreads();

    // phase 3: q[a][c] = b2 + sum_h z[a][h] * w2[a][h][c]
    if (t < N_AGENTS * N_ACT) {
        const int a = t / N_ACT, c = t % N_ACT;
        const float* w2p = w2 + a * (HID * N_ACT) + c;
        float acc = b2[a * N_ACT + c];
        #pragma unroll
        for (int hh = 0; hh < HID; ++hh) acc += zbuf[a][hh] * w2p[hh * N_ACT];
        qbuf[a][c] = acc;
    }
    __syncthreads();

    // phase 4: argmax over actions (first-max, matching jnp.argmax), gather
    if (t < N_AGENTS) {
        const float* ap = actions + ((size_t)t * BATCH + b) * N_ACT;
        int best = 0; float bv = ap[0];
        for (int c = 1; c < N_ACT; ++c) {
            float v = ap[c];
            if (v > bv) { bv = v; best = c; }
        }
        out[t * BATCH + b] = qbuf[t][best];
    }
}

extern "C" void kernel_launch(void* const* d_in, const int* in_sizes, int n_in,
                              void* d_out, int out_size, void* d_ws, size_t ws_size,
                              hipStream_t stream) {
    const float* u   = (const float*)d_in[0];
    // d_in[1] = binary_tensor: dead in the reference computation
    const float* act = (const float*)d_in[2];
    const float* gw  = (const float*)d_in[3];
    const float* gb  = (const float*)d_in[4];
    const float* w1  = (const float*)d_in[5];
    const float* b1  = (const float*)d_in[6];
    const float* w2  = (const float*)d_in[7];
    const float* b2  = (const float*)d_in[8];
    float* out = (float*)d_out;

    hipLaunchKernelGGL(k_fused, dim3(NCHUNK), dim3(512),  0, stream, u, gw);
    hipLaunchKernelGGL(k_tail,  dim3(BATCH),  dim3(1024), 0, stream,
                       gb, w1, b1, w2, b2, act, out);
}